// Round 14
// baseline (293.961 us; speedup 1.0000x reference)
//
#include <hip/hip_runtime.h>
#include <hip/hip_bf16.h>
#include <stdint.h>

#define D_MODEL 1024
#define NHEAD 16
#define HD 64
#define BATCH 2
#define SEQ 2048
#define MROWS (BATCH*SEQ)   // 4096

typedef __bf16 bf16x8 __attribute__((ext_vector_type(8)));
typedef float  f32x4  __attribute__((ext_vector_type(4)));
typedef unsigned short u16;

typedef __attribute__((address_space(3))) uint32_t       lds_u32_t;
typedef const __attribute__((address_space(1))) uint32_t glob_u32_t;

__device__ __forceinline__ u16 f2bf(float f) {
    union { float f; uint32_t u; } x; x.f = f;
    return (u16)((x.u + 0x7fffu + ((x.u >> 16) & 1u)) >> 16);
}

// ---------------- convert fp32 -> bf16 (single launch for all 7 tensors) ----
// Convert-once-read-many: GEMMs re-read operands 8-32x (R5 lesson).
__global__ void cvt_all(const float* __restrict__ q, const float* __restrict__ k,
                        const float* __restrict__ v, const float* __restrict__ wq,
                        const float* __restrict__ wk, const float* __restrict__ wv,
                        const float* __restrict__ wo, u16* __restrict__ Xb,
                        u16* __restrict__ Wb) {
    const int y = blockIdx.y;
    const float* src;
    u16* dst;
    int n4;
    if (y < 3) {
        src = (y == 0) ? q : (y == 1) ? k : v;
        dst = Xb + (size_t)y * (MROWS * D_MODEL);
        n4 = MROWS * D_MODEL / 4;
    } else {
        const int z = y - 3;
        src = (z == 0) ? wq : (z == 1) ? wk : (z == 2) ? wv : wo;
        dst = Wb + (size_t)z * (D_MODEL * D_MODEL);
        n4 = D_MODEL * D_MODEL / 4;
    }
    int idx = blockIdx.x * blockDim.x + threadIdx.x;
    int stride = gridDim.x * blockDim.x;
    for (int i = idx; i < n4; i += stride) {
        float4 vv = reinterpret_cast<const float4*>(src)[i];
        ushort4 o;
        o.x = f2bf(vv.x); o.y = f2bf(vv.y); o.z = f2bf(vv.z); o.w = f2bf(vv.w);
        reinterpret_cast<ushort4*>(dst)[i] = o;
    }
}

// Stage a [rows x 64] bf16 tile into linear LDS with XOR-pre-swizzled global
// source (T2, rule #21: linear dest + inverse-swz source + swz on read).
__device__ __forceinline__ void stage_swz(const u16* g, size_t ldk, u16* lds, int tid, int iters) {
    for (int it = 0; it < iters; ++it) {
        int c = it * 256 + tid;
        int row = c >> 3;
        int gc8 = ((c & 7) ^ (row & 7)) << 3;
        const u16* ga = g + (size_t)row * ldk + gc8;
        __builtin_amdgcn_global_load_lds((glob_u32_t*)ga, (lds_u32_t*)(lds + c * 8), 16, 0, 0);
    }
}

// Swizzled fragment read: row-major [*][64] bf16 tile, cc = 16B chunk col (0..7)
__device__ __forceinline__ bf16x8 lds_frag(const u16* lds, int row, int cc) {
    return *reinterpret_cast<const bf16x8*>(lds + row * 64 + (((cc ^ (row & 7))) << 3));
}

// ---------------- QKV projection GEMM (NT, bf16 MFMA) ----------------
__global__ __launch_bounds__(256) void proj_gemm(
    const u16* __restrict__ Xb, const u16* __restrict__ Wb,
    u16* __restrict__ qh, u16* __restrict__ kh, u16* __restrict__ vT)
{
    const int z = blockIdx.z;
    const u16* A = Xb + (size_t)z * MROWS * D_MODEL;
    const u16* W = Wb + (size_t)z * D_MODEL * D_MODEL;
    const int m0 = blockIdx.x * 128;
    const int n0 = blockIdx.y * 128;
    __shared__ __align__(16) u16 As[128 * 64];
    __shared__ __align__(16) u16 Bs[128 * 64];
    const int tid = threadIdx.x;
    const int l = tid & 63;
    const int w = tid >> 6;
    const int wr = (w >> 1) * 64, wc = (w & 1) * 64;
    const int lr = l & 15, lc = l >> 4;

    f32x4 acc[4][4];
    const f32x4 zero = {0.f, 0.f, 0.f, 0.f};
#pragma unroll
    for (int i = 0; i < 4; ++i)
#pragma unroll
        for (int j = 0; j < 4; ++j) acc[i][j] = zero;

    for (int kt = 0; kt < D_MODEL / 64; ++kt) {
        stage_swz(A + (size_t)m0 * D_MODEL + kt * 64, D_MODEL, As, tid, 4);
        stage_swz(W + (size_t)n0 * D_MODEL + kt * 64, D_MODEL, Bs, tid, 4);
        __syncthreads();
#pragma unroll
        for (int ks = 0; ks < 2; ++ks) {
            bf16x8 af[4], bfr[4];
#pragma unroll
            for (int mi = 0; mi < 4; ++mi) af[mi] = lds_frag(As, wr + mi * 16 + lr, ks * 4 + lc);
#pragma unroll
            for (int ni = 0; ni < 4; ++ni) bfr[ni] = lds_frag(Bs, wc + ni * 16 + lr, ks * 4 + lc);
            if (z < 2) {
#pragma unroll
                for (int mi = 0; mi < 4; ++mi)
#pragma unroll
                    for (int ni = 0; ni < 4; ++ni)
                        acc[mi][ni] = __builtin_amdgcn_mfma_f32_16x16x32_bf16(bfr[ni], af[mi], acc[mi][ni], 0, 0, 0);
            } else {
#pragma unroll
                for (int mi = 0; mi < 4; ++mi)
#pragma unroll
                    for (int ni = 0; ni < 4; ++ni)
                        acc[mi][ni] = __builtin_amdgcn_mfma_f32_16x16x32_bf16(af[mi], bfr[ni], acc[mi][ni], 0, 0, 0);
            }
        }
        __syncthreads();
    }

    if (z < 2) {
        const float sc = (z == 0) ? 0.125f : 1.0f;
        u16* dst = (z == 0) ? qh : kh;
#pragma unroll
        for (int mi = 0; mi < 4; ++mi) {
            const int srow = m0 + wr + mi * 16 + lr;
            const int bb = srow >> 11, ss = srow & 2047;
#pragma unroll
            for (int ni = 0; ni < 4; ++ni) {
                const int nbase = n0 + wc + ni * 16;
                const int hh = nbase >> 6;
                const int dbase = (nbase & 63) + lc * 4;
                ushort4 o;
                o.x = f2bf(acc[mi][ni][0] * sc); o.y = f2bf(acc[mi][ni][1] * sc);
                o.z = f2bf(acc[mi][ni][2] * sc); o.w = f2bf(acc[mi][ni][3] * sc);
                *reinterpret_cast<ushort4*>(&dst[(((size_t)(bb * NHEAD + hh)) * SEQ + ss) * HD + dbase]) = o;
            }
        }
    } else {
#pragma unroll
        for (int mi = 0; mi < 4; ++mi) {
            const int rbase = m0 + wr + mi * 16 + lc * 4;
            const int bb = rbase >> 11, ss = rbase & 2047;
#pragma unroll
            for (int ni = 0; ni < 4; ++ni) {
                const int col = n0 + wc + ni * 16 + lr;
                const int hh = col >> 6, dd = col & 63;
                ushort4 o;
                o.x = f2bf(acc[mi][ni][0]); o.y = f2bf(acc[mi][ni][1]);
                o.z = f2bf(acc[mi][ni][2]); o.w = f2bf(acc[mi][ni][3]);
                *reinterpret_cast<ushort4*>(&vT[(((size_t)(bb * NHEAD + hh)) * HD + dd) * SEQ + ss]) = o;
            }
        }
    }
}

// ---------------- fused attention: 8-wave QBLK=128 + defer-max (R8 exact, ---
// except: score stores are PLAIN (not nontemporal). A/B vs R8=236.9us:
// NT was bundled into R4 untested; hypothesis is no-allocate NT loses L2
// write-combining/absorption for the 537MB score stream (attn writes at
// 3.7TB/s vs fill's 6.7TB/s with plain stores).
__global__ __launch_bounds__(512, 4) void attn_kernel(
    const u16* __restrict__ qh, const u16* __restrict__ kh, const u16* __restrict__ vT,
    const int* __restrict__ mask, float* __restrict__ scores, u16* __restrict__ attn_out)
{
    const int bid = blockIdx.x;          // 0..511
    const int xcd = bid & 7;
    const int t = bid >> 3;              // 0..63
    const int h = t & 15;
    const int g = (t >> 4) * 8 + xcd;    // 0..31  (b, qtile): heads share mask tile per XCD
    const int b = g >> 4;
    const int qt = g & 15;

    const int tid = threadIdx.x;         // 0..511
    const int l = tid & 63;
    const int w = tid >> 6;              // 0..7
    const int lr = l & 15, lc = l >> 4;
    const int i0 = qt * 128 + w * 16;    // wave's 16 q-rows; this lane owns q = i0+lr

    const u16* qb = qh + ((size_t)(b * NHEAD + h)) * SEQ * HD;
    const u16* kb = kh + ((size_t)(b * NHEAD + h)) * SEQ * HD;
    const u16* vb = vT + ((size_t)(b * NHEAD + h)) * HD * SEQ;
    const int* mbase = mask + ((size_t)b * SEQ + (i0 + lr)) * SEQ;
    float* sbase = scores + (((size_t)(b * NHEAD + h)) * SEQ + (i0 + lr)) * SEQ;

    __shared__ __align__(16) u16 Ks[2][64 * 64];
    __shared__ __align__(16) u16 Vs[2][64 * 64];
    __shared__ __align__(16) uint32_t Plds[8][16 * 32];   // per-wave P scratch

    bf16x8 qf[2];
#pragma unroll
    for (int ks = 0; ks < 2; ++ks)
        qf[ks] = *reinterpret_cast<const bf16x8*>(&qb[(size_t)(i0 + lr) * HD + ks * 32 + (lc << 3)]);

    const f32x4 zero = {0.f, 0.f, 0.f, 0.f};
    f32x4 oacc[4];
#pragma unroll
    for (int i = 0; i < 4; ++i) oacc[i] = zero;
    float mrow = -1e30f, lrowv = 0.f;

    // prologue: stage tile 0 into buffer 0 (1 chunk/thread/tensor @512 threads)
    {
        int c = tid;
        int row = c >> 3;
        int gc8 = ((c & 7) ^ (row & 7)) << 3;
        __builtin_amdgcn_global_load_lds((glob_u32_t*)(kb + (size_t)row * HD + gc8),
                                         (lds_u32_t*)(Ks[0] + c * 8), 16, 0, 0);
        __builtin_amdgcn_global_load_lds((glob_u32_t*)(vb + (size_t)row * SEQ + gc8),
                                         (lds_u32_t*)(Vs[0] + c * 8), 16, 0, 0);
    }
    asm volatile("s_waitcnt vmcnt(0)" ::: "memory");
    __builtin_amdgcn_s_barrier();
    asm volatile("" ::: "memory");

    uint32_t* pw = Plds[w];
    const int rowb = lr * 32;
    const int swz = (lr & 7) << 2;

    int cur = 0;
    for (int jt = 0; jt < SEQ / 64; ++jt) {
        const int j0 = jt * 64;

        // (1) mask prefetch into regs (consumed after QK; covered by MFMA span)
        int4 mvv4[4];
        const int4* m4 = reinterpret_cast<const int4*>(mbase + j0);
#pragma unroll
        for (int nf = 0; nf < 4; ++nf) mvv4[nf] = m4[nf * 4 + lc];
        asm volatile("" ::: "memory");

        // (2) issue next K/V tile into the other buffer (1 chunk/thread/tensor)
        if (jt + 1 < SEQ / 64) {
            const int j1 = j0 + 64;
            u16* kd = Ks[cur ^ 1];
            u16* vd = Vs[cur ^ 1];
            int c = tid;
            int row = c >> 3;
            int gc8 = ((c & 7) ^ (row & 7)) << 3;
            __builtin_amdgcn_global_load_lds((glob_u32_t*)(kb + (size_t)(j1 + row) * HD + gc8),
                                             (lds_u32_t*)(kd + c * 8), 16, 0, 0);
            __builtin_amdgcn_global_load_lds((glob_u32_t*)(vb + (size_t)row * SEQ + j1 + gc8),
                                             (lds_u32_t*)(vd + c * 8), 16, 0, 0);
        }

        // (3) S^T = K q^T
        f32x4 sf[4];
#pragma unroll
        for (int nf = 0; nf < 4; ++nf) sf[nf] = zero;
        __builtin_amdgcn_s_setprio(1);
#pragma unroll
        for (int ks = 0; ks < 2; ++ks)
#pragma unroll
            for (int nf = 0; nf < 4; ++nf) {
                bf16x8 kf = lds_frag(Ks[cur], nf * 16 + lr, ks * 4 + lc);
                sf[nf] = __builtin_amdgcn_mfma_f32_16x16x32_bf16(kf, qf[ks], sf[nf], 0, 0, 0);
            }
        __builtin_amdgcn_s_setprio(0);

        // (4) mask + PLAIN float4 score stores + in-lane row max (the A/B diff)
        float rmax = -1e30f;
        float* srow = sbase + j0;
#pragma unroll
        for (int nf = 0; nf < 4; ++nf) {
            int mv[4] = {mvv4[nf].x, mvv4[nf].y, mvv4[nf].z, mvv4[nf].w};
#pragma unroll
            for (int r = 0; r < 4; ++r) {
                float s = sf[nf][r];
                s = (mv[r] == 0) ? -1e10f : s;
                sf[nf][r] = s;
                rmax = fmaxf(rmax, s);
            }
            *reinterpret_cast<f32x4*>(srow + nf * 16 + lc * 4) = sf[nf];
        }
        rmax = fmaxf(rmax, __shfl_xor(rmax, 16));
        rmax = fmaxf(rmax, __shfl_xor(rmax, 32));

        // (5) defer-max (T13): only rescale when some row's max grew > 8
        if (__any(rmax > mrow + 8.0f)) {
            float mnew = fmaxf(mrow, rmax);
            float ef = __expf(mrow - mnew);
            mrow = mnew;
            lrowv *= ef;
#pragma unroll
            for (int nf = 0; nf < 4; ++nf)
#pragma unroll
                for (int r = 0; r < 4; ++r) oacc[nf][r] *= ef;
        }

        // (6) P = exp(s-m): in-lane sum; pack to bf16 pairs via cvt_pk
        float psum = 0.f;
        uint32_t pk[4][2];
#pragma unroll
        for (int nf = 0; nf < 4; ++nf) {
            float p0 = __expf(sf[nf][0] - mrow);
            float p1 = __expf(sf[nf][1] - mrow);
            float p2 = __expf(sf[nf][2] - mrow);
            float p3 = __expf(sf[nf][3] - mrow);
            psum += (p0 + p1) + (p2 + p3);
            asm("v_cvt_pk_bf16_f32 %0, %1, %2" : "=v"(pk[nf][0]) : "v"(p0), "v"(p1));
            asm("v_cvt_pk_bf16_f32 %0, %1, %2" : "=v"(pk[nf][1]) : "v"(p2), "v"(p3));
        }
        psum += __shfl_xor(psum, 16);
        psum += __shfl_xor(psum, 32);
        lrowv += psum;

        // (7) P -> per-wave swizzled LDS, read back as PV B-fragments
#pragma unroll
        for (int nf = 0; nf < 4; ++nf) {
            uint2 uu = make_uint2(pk[nf][0], pk[nf][1]);
            *reinterpret_cast<uint2*>(&pw[rowb + ((nf * 8 + lc * 2) ^ swz)]) = uu;
        }
        bf16x8 pa[2];
#pragma unroll
        for (int ks = 0; ks < 2; ++ks)
            pa[ks] = *reinterpret_cast<const bf16x8*>(&pw[rowb + ((ks * 16 + lc * 4) ^ swz)]);

        // (8) O^T += V^T P^T
        __builtin_amdgcn_s_setprio(1);
#pragma unroll
        for (int ks = 0; ks < 2; ++ks)
#pragma unroll
            for (int nf = 0; nf < 4; ++nf) {
                bf16x8 vf = lds_frag(Vs[cur], nf * 16 + lr, ks * 4 + lc);
                oacc[nf] = __builtin_amdgcn_mfma_f32_16x16x32_bf16(vf, pa[ks], oacc[nf], 0, 0, 0);
            }
        __builtin_amdgcn_s_setprio(0);

        // (9) counted drain: retire stage loads; leave the 16 score stores
        //     (newest VMEM ops) in flight across the barrier.
        asm volatile("s_waitcnt vmcnt(16) lgkmcnt(0)" ::: "memory");
        __builtin_amdgcn_s_barrier();
        asm volatile("" ::: "memory");
        cur ^= 1;
    }

    // epilogue: all in-lane; 4x ushort4 stores
    const float linv = __builtin_amdgcn_rcpf(lrowv);
    const size_t orow = (size_t)(b * SEQ + i0 + lr) * D_MODEL + h * HD;
#pragma unroll
    for (int nf = 0; nf < 4; ++nf) {
        ushort4 o;
        o.x = f2bf(oacc[nf][0] * linv); o.y = f2bf(oacc[nf][1] * linv);
        o.z = f2bf(oacc[nf][2] * linv); o.w = f2bf(oacc[nf][3] * linv);
        *reinterpret_cast<ushort4*>(&attn_out[orow + nf * 16 + lc * 4]) = o;
    }
}

// ---------------- output projection + residual (128x64 tiles, 512 blocks) ----
__global__ __launch_bounds__(256) void out_proj_gemm(
    const u16* __restrict__ Ab, const u16* __restrict__ Wo,
    const float* __restrict__ resid, float* __restrict__ outp)
{
    const int m0 = blockIdx.x * 128;
    const int n0 = blockIdx.y * 64;
    __shared__ __align__(16) u16 As[128 * 64];
    __shared__ __align__(16) u16 Bs[64 * 64];
    const int tid = threadIdx.x;
    const int l = tid & 63;
    const int w = tid >> 6;
    const int wr = (w >> 1) * 64, wc = (w & 1) * 32;
    const int lr = l & 15, lc = l >> 4;

    f32x4 acc[4][2];
    const f32x4 zero = {0.f, 0.f, 0.f, 0.f};
#pragma unroll
    for (int i = 0; i < 4; ++i)
#pragma unroll
        for (int j = 0; j < 2; ++j) acc[i][j] = zero;

    for (int kt = 0; kt < D_MODEL / 64; ++kt) {
        stage_swz(Ab + (size_t)m0 * D_MODEL + kt * 64, D_MODEL, As, tid, 4);
        stage_swz(Wo + (size_t)n0 * D_MODEL + kt * 64, D_MODEL, Bs, tid, 2);
        __syncthreads();
#pragma unroll
        for (int ks = 0; ks < 2; ++ks) {
            bf16x8 af[4], bfr[2];
#pragma unroll
            for (int mi = 0; mi < 4; ++mi) af[mi] = lds_frag(As, wr + mi * 16 + lr, ks * 4 + lc);
#pragma unroll
            for (int ni = 0; ni < 2; ++ni) bfr[ni] = lds_frag(Bs, wc + ni * 16 + lr, ks * 4 + lc);
#pragma unroll
            for (int mi = 0; mi < 4; ++mi)
#pragma unroll
                for (int ni = 0; ni < 2; ++ni)
                    acc[mi][ni] = __builtin_amdgcn_mfma_f32_16x16x32_bf16(af[mi], bfr[ni], acc[mi][ni], 0, 0, 0);
        }
        __syncthreads();
    }

#pragma unroll
    for (int mi = 0; mi < 4; ++mi)
#pragma unroll
        for (int ni = 0; ni < 2; ++ni)
#pragma unroll
            for (int r = 0; r < 4; ++r) {
                const int row = m0 + wr + mi * 16 + lc * 4 + r;
                const int col = n0 + wc + ni * 16 + lr;
                const size_t idx = (size_t)row * D_MODEL + col;
                __builtin_nontemporal_store(acc[mi][ni][r] + resid[idx], &outp[idx]);
            }
}

extern "C" void kernel_launch(void* const* d_in, const int* in_sizes, int n_in,
                              void* d_out, int out_size, void* d_ws, size_t ws_size,
                              hipStream_t stream) {
    (void)in_sizes; (void)n_in; (void)out_size; (void)ws_size;
    const float* Q  = (const float*)d_in[0];
    const float* K  = (const float*)d_in[1];
    const float* V  = (const float*)d_in[2];
    const float* Wq = (const float*)d_in[3];
    const float* Wk = (const float*)d_in[4];
    const float* Wv = (const float*)d_in[5];
    const float* Wo = (const float*)d_in[6];
    const int* mask = (const int*)d_in[7];

    const size_t NX = (size_t)MROWS * D_MODEL;      // 4,194,304
    const size_t NW = (size_t)D_MODEL * D_MODEL;    // 1,048,576

    u16* Xb  = (u16*)d_ws;          // 3 * NX bf16
    u16* Wb  = Xb + 3 * NX;         // 4 * NW bf16
    u16* qhp = Wb + 4 * NW;         // NX
    u16* khp = qhp + NX;            // NX
    u16* vTp = khp + NX;            // NX
    u16* aout = vTp + NX;           // NX

    float* outp   = (float*)d_out;
    float* scores = outp + NX;

    cvt_all<<<dim3(1024, 7), dim3(256), 0, stream>>>(Q, K, V, Wq, Wk, Wv, Wo, Xb, Wb);
    proj_gemm<<<dim3(32, 8, 3), dim3(256), 0, stream>>>(Xb, Wb, qhp, khp, vTp);
    attn_kernel<<<dim3(512), dim3(512), 0, stream>>>(qhp, khp, vTp, mask, scores, aout);
    out_proj_gemm<<<dim3(32, 16), dim3(256), 0, stream>>>(aout, Wb + 3 * NW, Q, outp);
}

// Round 15
// 235.909 us; speedup vs baseline: 1.2461x; 1.2461x over previous
//
#include <hip/hip_runtime.h>
#include <hip/hip_bf16.h>
#include <stdint.h>

#define D_MODEL 1024
#define NHEAD 16
#define HD 64
#define BATCH 2
#define SEQ 2048
#define MROWS (BATCH*SEQ)   // 4096

typedef __bf16 bf16x8 __attribute__((ext_vector_type(8)));
typedef float  f32x4  __attribute__((ext_vector_type(4)));
typedef unsigned short u16;

typedef __attribute__((address_space(3))) uint32_t       lds_u32_t;
typedef const __attribute__((address_space(1))) uint32_t glob_u32_t;

__device__ __forceinline__ u16 f2bf(float f) {
    union { float f; uint32_t u; } x; x.f = f;
    return (u16)((x.u + 0x7fffu + ((x.u >> 16) & 1u)) >> 16);
}

// ---------------- convert fp32 -> bf16 (single launch for all 7 tensors) ----
// Convert-once-read-many: GEMMs re-read operands 8-32x (R5 lesson).
__global__ void cvt_all(const float* __restrict__ q, const float* __restrict__ k,
                        const float* __restrict__ v, const float* __restrict__ wq,
                        const float* __restrict__ wk, const float* __restrict__ wv,
                        const float* __restrict__ wo, u16* __restrict__ Xb,
                        u16* __restrict__ Wb) {
    const int y = blockIdx.y;
    const float* src;
    u16* dst;
    int n4;
    if (y < 3) {
        src = (y == 0) ? q : (y == 1) ? k : v;
        dst = Xb + (size_t)y * (MROWS * D_MODEL);
        n4 = MROWS * D_MODEL / 4;
    } else {
        const int z = y - 3;
        src = (z == 0) ? wq : (z == 1) ? wk : (z == 2) ? wv : wo;
        dst = Wb + (size_t)z * (D_MODEL * D_MODEL);
        n4 = D_MODEL * D_MODEL / 4;
    }
    int idx = blockIdx.x * blockDim.x + threadIdx.x;
    int stride = gridDim.x * blockDim.x;
    for (int i = idx; i < n4; i += stride) {
        float4 vv = reinterpret_cast<const float4*>(src)[i];
        ushort4 o;
        o.x = f2bf(vv.x); o.y = f2bf(vv.y); o.z = f2bf(vv.z); o.w = f2bf(vv.w);
        reinterpret_cast<ushort4*>(dst)[i] = o;
    }
}

// Stage a [rows x 64] bf16 tile into linear LDS with XOR-pre-swizzled global
// source (T2, rule #21: linear dest + inverse-swz source + swz on read).
__device__ __forceinline__ void stage_swz(const u16* g, size_t ldk, u16* lds, int tid, int iters) {
    for (int it = 0; it < iters; ++it) {
        int c = it * 256 + tid;
        int row = c >> 3;
        int gc8 = ((c & 7) ^ (row & 7)) << 3;
        const u16* ga = g + (size_t)row * ldk + gc8;
        __builtin_amdgcn_global_load_lds((glob_u32_t*)ga, (lds_u32_t*)(lds + c * 8), 16, 0, 0);
    }
}

// Swizzled fragment read: row-major [*][64] bf16 tile, cc = 16B chunk col (0..7)
__device__ __forceinline__ bf16x8 lds_frag(const u16* lds, int row, int cc) {
    return *reinterpret_cast<const bf16x8*>(lds + row * 64 + (((cc ^ (row & 7))) << 3));
}

// ---------------- QKV projection GEMM (NT, bf16 MFMA) ----------------
// z=0: q=(X@Wq^T)*0.125 -> qh[b,h,s,d]; z=1: kh; z=2: vT[b,h,d,s]
// z<2 uses swapped operands (mfma(W,X)) so each lane holds 4 consecutive d.
__global__ __launch_bounds__(256) void proj_gemm(
    const u16* __restrict__ Xb, const u16* __restrict__ Wb,
    u16* __restrict__ qh, u16* __restrict__ kh, u16* __restrict__ vT)
{
    const int z = blockIdx.z;
    const u16* A = Xb + (size_t)z * MROWS * D_MODEL;
    const u16* W = Wb + (size_t)z * D_MODEL * D_MODEL;
    const int m0 = blockIdx.x * 128;
    const int n0 = blockIdx.y * 128;
    __shared__ __align__(16) u16 As[128 * 64];
    __shared__ __align__(16) u16 Bs[128 * 64];
    const int tid = threadIdx.x;
    const int l = tid & 63;
    const int w = tid >> 6;
    const int wr = (w >> 1) * 64, wc = (w & 1) * 64;
    const int lr = l & 15, lc = l >> 4;

    f32x4 acc[4][4];
    const f32x4 zero = {0.f, 0.f, 0.f, 0.f};
#pragma unroll
    for (int i = 0; i < 4; ++i)
#pragma unroll
        for (int j = 0; j < 4; ++j) acc[i][j] = zero;

    for (int kt = 0; kt < D_MODEL / 64; ++kt) {
        stage_swz(A + (size_t)m0 * D_MODEL + kt * 64, D_MODEL, As, tid, 4);
        stage_swz(W + (size_t)n0 * D_MODEL + kt * 64, D_MODEL, Bs, tid, 4);
        __syncthreads();
#pragma unroll
        for (int ks = 0; ks < 2; ++ks) {
            bf16x8 af[4], bfr[4];
#pragma unroll
            for (int mi = 0; mi < 4; ++mi) af[mi] = lds_frag(As, wr + mi * 16 + lr, ks * 4 + lc);
#pragma unroll
            for (int ni = 0; ni < 4; ++ni) bfr[ni] = lds_frag(Bs, wc + ni * 16 + lr, ks * 4 + lc);
            if (z < 2) {
#pragma unroll
                for (int mi = 0; mi < 4; ++mi)
#pragma unroll
                    for (int ni = 0; ni < 4; ++ni)
                        acc[mi][ni] = __builtin_amdgcn_mfma_f32_16x16x32_bf16(bfr[ni], af[mi], acc[mi][ni], 0, 0, 0);
            } else {
#pragma unroll
                for (int mi = 0; mi < 4; ++mi)
#pragma unroll
                    for (int ni = 0; ni < 4; ++ni)
                        acc[mi][ni] = __builtin_amdgcn_mfma_f32_16x16x32_bf16(af[mi], bfr[ni], acc[mi][ni], 0, 0, 0);
            }
        }
        __syncthreads();
    }

    if (z < 2) {
        const float sc = (z == 0) ? 0.125f : 1.0f;
        u16* dst = (z == 0) ? qh : kh;
#pragma unroll
        for (int mi = 0; mi < 4; ++mi) {
            const int srow = m0 + wr + mi * 16 + lr;
            const int bb = srow >> 11, ss = srow & 2047;
#pragma unroll
            for (int ni = 0; ni < 4; ++ni) {
                const int nbase = n0 + wc + ni * 16;
                const int hh = nbase >> 6;
                const int dbase = (nbase & 63) + lc * 4;
                ushort4 o;
                o.x = f2bf(acc[mi][ni][0] * sc); o.y = f2bf(acc[mi][ni][1] * sc);
                o.z = f2bf(acc[mi][ni][2] * sc); o.w = f2bf(acc[mi][ni][3] * sc);
                *reinterpret_cast<ushort4*>(&dst[(((size_t)(bb * NHEAD + hh)) * SEQ + ss) * HD + dbase]) = o;
            }
        }
    } else {
#pragma unroll
        for (int mi = 0; mi < 4; ++mi) {
            const int rbase = m0 + wr + mi * 16 + lc * 4;
            const int bb = rbase >> 11, ss = rbase & 2047;
#pragma unroll
            for (int ni = 0; ni < 4; ++ni) {
                const int col = n0 + wc + ni * 16 + lr;
                const int hh = col >> 6, dd = col & 63;
                ushort4 o;
                o.x = f2bf(acc[mi][ni][0]); o.y = f2bf(acc[mi][ni][1]);
                o.z = f2bf(acc[mi][ni][2]); o.w = f2bf(acc[mi][ni][3]);
                *reinterpret_cast<ushort4*>(&vT[(((size_t)(bb * NHEAD + hh)) * HD + dd) * SEQ + ss]) = o;
            }
        }
    }
}

// ---------------- fused attention: 8-wave QBLK=128 + defer-max (R8 exact) ---
// Swapped QK^T and swapped PV (all softmax state in-lane, q-row = lane&15).
// 8 waves share one K/V stage; NT score stores (no-allocate: keeps the 537MB
// write-once stream out of the per-XCD L2 that K/V/mask reuse — R14 A/B:
// plain stores cost +57us); vmcnt(16) leaves stores in flight across barrier.
__global__ __launch_bounds__(512, 4) void attn_kernel(
    const u16* __restrict__ qh, const u16* __restrict__ kh, const u16* __restrict__ vT,
    const int* __restrict__ mask, float* __restrict__ scores, u16* __restrict__ attn_out)
{
    const int bid = blockIdx.x;          // 0..511
    const int xcd = bid & 7;
    const int t = bid >> 3;              // 0..63
    const int h = t & 15;
    const int g = (t >> 4) * 8 + xcd;    // 0..31  (b, qtile): heads share mask tile per XCD
    const int b = g >> 4;
    const int qt = g & 15;

    const int tid = threadIdx.x;         // 0..511
    const int l = tid & 63;
    const int w = tid >> 6;              // 0..7
    const int lr = l & 15, lc = l >> 4;
    const int i0 = qt * 128 + w * 16;    // wave's 16 q-rows; this lane owns q = i0+lr

    const u16* qb = qh + ((size_t)(b * NHEAD + h)) * SEQ * HD;
    const u16* kb = kh + ((size_t)(b * NHEAD + h)) * SEQ * HD;
    const u16* vb = vT + ((size_t)(b * NHEAD + h)) * HD * SEQ;
    const int* mbase = mask + ((size_t)b * SEQ + (i0 + lr)) * SEQ;
    float* sbase = scores + (((size_t)(b * NHEAD + h)) * SEQ + (i0 + lr)) * SEQ;

    __shared__ __align__(16) u16 Ks[2][64 * 64];
    __shared__ __align__(16) u16 Vs[2][64 * 64];
    __shared__ __align__(16) uint32_t Plds[8][16 * 32];   // per-wave P scratch

    bf16x8 qf[2];
#pragma unroll
    for (int ks = 0; ks < 2; ++ks)
        qf[ks] = *reinterpret_cast<const bf16x8*>(&qb[(size_t)(i0 + lr) * HD + ks * 32 + (lc << 3)]);

    const f32x4 zero = {0.f, 0.f, 0.f, 0.f};
    f32x4 oacc[4];
#pragma unroll
    for (int i = 0; i < 4; ++i) oacc[i] = zero;
    float mrow = -1e30f, lrowv = 0.f;

    // prologue: stage tile 0 into buffer 0 (1 chunk/thread/tensor @512 threads)
    {
        int c = tid;
        int row = c >> 3;
        int gc8 = ((c & 7) ^ (row & 7)) << 3;
        __builtin_amdgcn_global_load_lds((glob_u32_t*)(kb + (size_t)row * HD + gc8),
                                         (lds_u32_t*)(Ks[0] + c * 8), 16, 0, 0);
        __builtin_amdgcn_global_load_lds((glob_u32_t*)(vb + (size_t)row * SEQ + gc8),
                                         (lds_u32_t*)(Vs[0] + c * 8), 16, 0, 0);
    }
    asm volatile("s_waitcnt vmcnt(0)" ::: "memory");
    __builtin_amdgcn_s_barrier();
    asm volatile("" ::: "memory");

    uint32_t* pw = Plds[w];
    const int rowb = lr * 32;
    const int swz = (lr & 7) << 2;

    int cur = 0;
    for (int jt = 0; jt < SEQ / 64; ++jt) {
        const int j0 = jt * 64;

        // (1) mask prefetch into regs (consumed after QK; covered by MFMA span)
        int4 mvv4[4];
        const int4* m4 = reinterpret_cast<const int4*>(mbase + j0);
#pragma unroll
        for (int nf = 0; nf < 4; ++nf) mvv4[nf] = m4[nf * 4 + lc];
        asm volatile("" ::: "memory");

        // (2) issue next K/V tile into the other buffer (1 chunk/thread/tensor)
        if (jt + 1 < SEQ / 64) {
            const int j1 = j0 + 64;
            u16* kd = Ks[cur ^ 1];
            u16* vd = Vs[cur ^ 1];
            int c = tid;
            int row = c >> 3;
            int gc8 = ((c & 7) ^ (row & 7)) << 3;
            __builtin_amdgcn_global_load_lds((glob_u32_t*)(kb + (size_t)(j1 + row) * HD + gc8),
                                             (lds_u32_t*)(kd + c * 8), 16, 0, 0);
            __builtin_amdgcn_global_load_lds((glob_u32_t*)(vb + (size_t)row * SEQ + j1 + gc8),
                                             (lds_u32_t*)(vd + c * 8), 16, 0, 0);
        }

        // (3) S^T = K q^T
        f32x4 sf[4];
#pragma unroll
        for (int nf = 0; nf < 4; ++nf) sf[nf] = zero;
        __builtin_amdgcn_s_setprio(1);
#pragma unroll
        for (int ks = 0; ks < 2; ++ks)
#pragma unroll
            for (int nf = 0; nf < 4; ++nf) {
                bf16x8 kf = lds_frag(Ks[cur], nf * 16 + lr, ks * 4 + lc);
                sf[nf] = __builtin_amdgcn_mfma_f32_16x16x32_bf16(kf, qf[ks], sf[nf], 0, 0, 0);
            }
        __builtin_amdgcn_s_setprio(0);

        // (4) mask + NT float4 score stores + in-lane row max
        float rmax = -1e30f;
        float* srow = sbase + j0;
#pragma unroll
        for (int nf = 0; nf < 4; ++nf) {
            int mv[4] = {mvv4[nf].x, mvv4[nf].y, mvv4[nf].z, mvv4[nf].w};
#pragma unroll
            for (int r = 0; r < 4; ++r) {
                float s = sf[nf][r];
                s = (mv[r] == 0) ? -1e10f : s;
                sf[nf][r] = s;
                rmax = fmaxf(rmax, s);
            }
            __builtin_nontemporal_store(sf[nf], reinterpret_cast<f32x4*>(srow + nf * 16 + lc * 4));
        }
        rmax = fmaxf(rmax, __shfl_xor(rmax, 16));
        rmax = fmaxf(rmax, __shfl_xor(rmax, 32));

        // (5) defer-max (T13): only rescale when some row's max grew > 8
        if (__any(rmax > mrow + 8.0f)) {
            float mnew = fmaxf(mrow, rmax);
            float ef = __expf(mrow - mnew);
            mrow = mnew;
            lrowv *= ef;
#pragma unroll
            for (int nf = 0; nf < 4; ++nf)
#pragma unroll
                for (int r = 0; r < 4; ++r) oacc[nf][r] *= ef;
        }

        // (6) P = exp(s-m): in-lane sum; pack to bf16 pairs via cvt_pk
        float psum = 0.f;
        uint32_t pk[4][2];
#pragma unroll
        for (int nf = 0; nf < 4; ++nf) {
            float p0 = __expf(sf[nf][0] - mrow);
            float p1 = __expf(sf[nf][1] - mrow);
            float p2 = __expf(sf[nf][2] - mrow);
            float p3 = __expf(sf[nf][3] - mrow);
            psum += (p0 + p1) + (p2 + p3);
            asm("v_cvt_pk_bf16_f32 %0, %1, %2" : "=v"(pk[nf][0]) : "v"(p0), "v"(p1));
            asm("v_cvt_pk_bf16_f32 %0, %1, %2" : "=v"(pk[nf][1]) : "v"(p2), "v"(p3));
        }
        psum += __shfl_xor(psum, 16);
        psum += __shfl_xor(psum, 32);
        lrowv += psum;

        // (7) P -> per-wave swizzled LDS, read back as PV B-fragments
#pragma unroll
        for (int nf = 0; nf < 4; ++nf) {
            uint2 uu = make_uint2(pk[nf][0], pk[nf][1]);
            *reinterpret_cast<uint2*>(&pw[rowb + ((nf * 8 + lc * 2) ^ swz)]) = uu;
        }
        bf16x8 pa[2];
#pragma unroll
        for (int ks = 0; ks < 2; ++ks)
            pa[ks] = *reinterpret_cast<const bf16x8*>(&pw[rowb + ((ks * 16 + lc * 4) ^ swz)]);

        // (8) O^T += V^T P^T
        __builtin_amdgcn_s_setprio(1);
#pragma unroll
        for (int ks = 0; ks < 2; ++ks)
#pragma unroll
            for (int nf = 0; nf < 4; ++nf) {
                bf16x8 vf = lds_frag(Vs[cur], nf * 16 + lr, ks * 4 + lc);
                oacc[nf] = __builtin_amdgcn_mfma_f32_16x16x32_bf16(vf, pa[ks], oacc[nf], 0, 0, 0);
            }
        __builtin_amdgcn_s_setprio(0);

        // (9) counted drain: retire stage loads; leave NT stores in flight
        asm volatile("s_waitcnt vmcnt(16) lgkmcnt(0)" ::: "memory");
        __builtin_amdgcn_s_barrier();
        asm volatile("" ::: "memory");
        cur ^= 1;
    }

    // epilogue: all in-lane; 4x ushort4 stores
    const float linv = __builtin_amdgcn_rcpf(lrowv);
    const size_t orow = (size_t)(b * SEQ + i0 + lr) * D_MODEL + h * HD;
#pragma unroll
    for (int nf = 0; nf < 4; ++nf) {
        ushort4 o;
        o.x = f2bf(oacc[nf][0] * linv); o.y = f2bf(oacc[nf][1] * linv);
        o.z = f2bf(oacc[nf][2] * linv); o.w = f2bf(oacc[nf][3] * linv);
        *reinterpret_cast<ushort4*>(&attn_out[orow + nf * 16 + lc * 4]) = o;
    }
}

// ---------------- output projection + residual (128x64 tiles, 512 blocks) ----
__global__ __launch_bounds__(256) void out_proj_gemm(
    const u16* __restrict__ Ab, const u16* __restrict__ Wo,
    const float* __restrict__ resid, float* __restrict__ outp)
{
    const int m0 = blockIdx.x * 128;
    const int n0 = blockIdx.y * 64;
    __shared__ __align__(16) u16 As[128 * 64];
    __shared__ __align__(16) u16 Bs[64 * 64];
    const int tid = threadIdx.x;
    const int l = tid & 63;
    const int w = tid >> 6;
    const int wr = (w >> 1) * 64, wc = (w & 1) * 32;
    const int lr = l & 15, lc = l >> 4;

    f32x4 acc[4][2];
    const f32x4 zero = {0.f, 0.f, 0.f, 0.f};
#pragma unroll
    for (int i = 0; i < 4; ++i)
#pragma unroll
        for (int j = 0; j < 2; ++j) acc[i][j] = zero;

    for (int kt = 0; kt < D_MODEL / 64; ++kt) {
        stage_swz(Ab + (size_t)m0 * D_MODEL + kt * 64, D_MODEL, As, tid, 4);
        stage_swz(Wo + (size_t)n0 * D_MODEL + kt * 64, D_MODEL, Bs, tid, 2);
        __syncthreads();
#pragma unroll
        for (int ks = 0; ks < 2; ++ks) {
            bf16x8 af[4], bfr[2];
#pragma unroll
            for (int mi = 0; mi < 4; ++mi) af[mi] = lds_frag(As, wr + mi * 16 + lr, ks * 4 + lc);
#pragma unroll
            for (int ni = 0; ni < 2; ++ni) bfr[ni] = lds_frag(Bs, wc + ni * 16 + lr, ks * 4 + lc);
#pragma unroll
            for (int mi = 0; mi < 4; ++mi)
#pragma unroll
                for (int ni = 0; ni < 2; ++ni)
                    acc[mi][ni] = __builtin_amdgcn_mfma_f32_16x16x32_bf16(af[mi], bfr[ni], acc[mi][ni], 0, 0, 0);
        }
        __syncthreads();
    }

#pragma unroll
    for (int mi = 0; mi < 4; ++mi)
#pragma unroll
        for (int ni = 0; ni < 2; ++ni)
#pragma unroll
            for (int r = 0; r < 4; ++r) {
                const int row = m0 + wr + mi * 16 + lc * 4 + r;
                const int col = n0 + wc + ni * 16 + lr;
                const size_t idx = (size_t)row * D_MODEL + col;
                __builtin_nontemporal_store(acc[mi][ni][r] + resid[idx], &outp[idx]);
            }
}

extern "C" void kernel_launch(void* const* d_in, const int* in_sizes, int n_in,
                              void* d_out, int out_size, void* d_ws, size_t ws_size,
                              hipStream_t stream) {
    (void)in_sizes; (void)n_in; (void)out_size; (void)ws_size;
    const float* Q  = (const float*)d_in[0];
    const float* K  = (const float*)d_in[1];
    const float* V  = (const float*)d_in[2];
    const float* Wq = (const float*)d_in[3];
    const float* Wk = (const float*)d_in[4];
    const float* Wv = (const float*)d_in[5];
    const float* Wo = (const float*)d_in[6];
    const int* mask = (const int*)d_in[7];

    const size_t NX = (size_t)MROWS * D_MODEL;      // 4,194,304
    const size_t NW = (size_t)D_MODEL * D_MODEL;    // 1,048,576

    u16* Xb  = (u16*)d_ws;          // 3 * NX bf16
    u16* Wb  = Xb + 3 * NX;         // 4 * NW bf16
    u16* qhp = Wb + 4 * NW;         // NX
    u16* khp = qhp + NX;            // NX
    u16* vTp = khp + NX;            // NX
    u16* aout = vTp + NX;           // NX

    float* outp   = (float*)d_out;
    float* scores = outp + NX;

    cvt_all<<<dim3(1024, 7), dim3(256), 0, stream>>>(Q, K, V, Wq, Wk, Wv, Wo, Xb, Wb);
    proj_gemm<<<dim3(32, 8, 3), dim3(256), 0, stream>>>(Xb, Wb, qhp, khp, vTp);
    attn_kernel<<<dim3(512), dim3(512), 0, stream>>>(qhp, khp, vTp, mask, scores, aout);
    out_proj_gemm<<<dim3(32, 16), dim3(256), 0, stream>>>(aout, Wb + 3 * NW, Q, outp);
}